// Round 3
// baseline (145.312 us; speedup 1.0000x reference)
//
#include <hip/hip_runtime.h>

// out = mean_i( rank_of_diag(cos_sim(x1,x2))_i < nper ), nper = S/100+1.
// rank_i = #{ j != i : dot(x1_i,x2_j)*inv||x2_j|| > dot(x1_i,x2_i)*inv||x2_i|| }
// GEMM via fp16x3 (Markidis split) MFMA: x=hi+lo; hi*hi + hi*lo + lo*hi.
// Dropped lo*lo ~2^-22 rel/term -> dot err ~3e-6 << 4.5e-3 order-stat spacing.
//
// R3: planes stored FRAGMENT-MAJOR in global memory (prep pre-swizzles into
// MFMA fragment order). Count kernel: A fragments -> 32 coalesced dwordx4
// loads straight to registers (128 VGPR, K=128 fully resident); B tile is a
// contiguous 32KB/plane span -> global_load_lds identity DMA into LDS. ONE
// barrier total; 96 MFMAs + 32 conflict-free ds_read_b128 run sync-free.
// (R2 analysis: MFMA busy == 20.5us floor, 8 barriers/block serialized the
// rest. This removes 7 of 8 barriers and halves LDS traffic.)
//
// Fragment-major plane layout (per plane, halves):
//   addr(row,k) = (row>>5)*4096 + ((k>>5)*2 + ((k>>4)&1))*512
//               + ((k>>3)&1)*256 + (row&31)*8 + (k&7)
// so a wave's 32x16 fragment (rows r0..r0+31, k-halves k0..k0+15) is one
// contiguous 1KB block read as ds_read_b128 / dwordx4 at base + lane*8.

#define KDIM 128

typedef _Float16 half8 __attribute__((ext_vector_type(8)));
typedef float floatx16 __attribute__((ext_vector_type(16)));

static __device__ __forceinline__ void gload16(const void* g, void* l)
{
    __builtin_amdgcn_global_load_lds(
        (__attribute__((address_space(1))) void*)(g),
        (__attribute__((address_space(3))) void*)(l),
        16, 0, 0);
}

// ---------- Kernel A: 1/||x2||, diag threshold, zero counters, fragment-major fp16 planes ----------
__global__ __launch_bounds__(256) void prep_kernel(
    const float* __restrict__ x1, const float* __restrict__ x2,
    float* __restrict__ invn, float* __restrict__ thr,
    int* __restrict__ row_count,
    unsigned* __restrict__ x1h, unsigned* __restrict__ x1l,
    unsigned* __restrict__ x2h, unsigned* __restrict__ x2l,
    int B, int S, int wplanes)
{
    const int wave = threadIdx.x >> 6;
    const int lane = threadIdx.x & 63;
    const int row = blockIdx.x * 4 + wave;
    if (row >= S && row >= B) return;

    float s22 = 0.f, s12 = 0.f;
    float2 a = make_float2(0.f, 0.f), b = make_float2(0.f, 0.f);
    if (row < B) a = ((const float2*)&x1[(size_t)row * KDIM])[lane];
    if (row < S) {
        b = ((const float2*)&x2[(size_t)row * KDIM])[lane];
        s22 = fmaf(b.x, b.x, b.y * b.y);
        s12 = fmaf(a.x, b.x, a.y * b.y);
    }

    if (wplanes) {
        // k = 2*lane, pair (k,k+1) shares one u32 slot.
        // u32 index: br*2048 + (c*2+ks2)*256 + hw*128 + fr*4 + q
        const int iu = (row >> 5) * 2048
                     + ((lane >> 4) * 2 + ((lane >> 3) & 1)) * 256
                     + ((lane >> 2) & 1) * 128
                     + (row & 31) * 4 + (lane & 3);
        if (row < B) {
            union { _Float16 h[2]; unsigned u; } hh, ll;
            hh.h[0] = (_Float16)a.x; ll.h[0] = (_Float16)(a.x - (float)hh.h[0]);
            hh.h[1] = (_Float16)a.y; ll.h[1] = (_Float16)(a.y - (float)hh.h[1]);
            x1h[iu] = hh.u;
            x1l[iu] = ll.u;
        }
        if (row < S) {
            union { _Float16 h[2]; unsigned u; } hh, ll;
            hh.h[0] = (_Float16)b.x; ll.h[0] = (_Float16)(b.x - (float)hh.h[0]);
            hh.h[1] = (_Float16)b.y; ll.h[1] = (_Float16)(b.y - (float)hh.h[1]);
            x2h[iu] = hh.u;
            x2l[iu] = ll.u;
        }
    }

    #pragma unroll
    for (int m = 32; m > 0; m >>= 1) {
        s22 += __shfl_xor(s22, m);
        s12 += __shfl_xor(s12, m);
    }
    if (lane == 0) {
        if (row < S) {
            float iv = rsqrtf(s22);
            invn[row] = iv;
            if (row < B) thr[row] = s12 * iv;
        }
        if (row < B) row_count[row] = 0;
    }
}

// ---------- Kernel B (fast): A-in-reg, B-DMA, single-barrier fp16x3 GEMM + count ----------
// 128x128 tile, 4 waves of 64x64 (2x2 of 32x32). K=128 resident:
// A frags in 128 VGPRs, B tile (64KB hi+lo) staged once via global_load_lds.
__global__ __launch_bounds__(256, 2) void count_kernel_fast(
    const _Float16* __restrict__ x1h, const _Float16* __restrict__ x1l,
    const _Float16* __restrict__ x2h, const _Float16* __restrict__ x2l,
    const float* __restrict__ invn, const float* __restrict__ thr,
    int* __restrict__ row_count)
{
    __shared__ __align__(16) _Float16 Bh[16384], Bl[16384];  // 64 KB
    __shared__ float s_thr[128], s_invn[128];
    __shared__ int cnt_s[128];

    const int tid  = threadIdx.x;
    const int wave = tid >> 6;
    const int lane = tid & 63;
    const int row0 = blockIdx.y * 128;
    const int col0 = blockIdx.x * 128;
    const int wr = (wave >> 1) * 64;   // wave row offset
    const int wc = (wave & 1) * 64;    // wave col offset

    if (tid < 128) {
        cnt_s[tid]  = 0;
        s_thr[tid]  = thr[row0 + tid];
        s_invn[tid] = invn[col0 + tid];
    }

    // ---- B tile DMA: contiguous 32KB per plane; wave w copies its 8KB quarter ----
    const size_t colbase = (size_t)(col0 >> 5) * 4096;
    {
        const int woff = wave * 4096;              // halves
        #pragma unroll
        for (int i = 0; i < 8; i++) {
            const int off = woff + i * 512;
            gload16(x2h + colbase + off + lane * 8, &Bh[off]);
        }
        #pragma unroll
        for (int i = 0; i < 8; i++) {
            const int off = woff + i * 512;
            gload16(x2l + colbase + off + lane * 8, &Bl[off]);
        }
    }

    // ---- A fragments: 32 coalesced dwordx4 loads -> registers (K=128 resident) ----
    const size_t abase = (size_t)((row0 + wr) >> 5) * 4096 + (size_t)lane * 8;
    half8 afh[2][4][2], afl[2][4][2];
    #pragma unroll
    for (int u = 0; u < 2; u++)
        #pragma unroll
        for (int c = 0; c < 4; c++)
            #pragma unroll
            for (int k2 = 0; k2 < 2; k2++) {
                const size_t o = abase + (size_t)u * 4096 + (c * 2 + k2) * 512;
                afh[u][c][k2] = *(const half8*)(x1h + o);
                afl[u][c][k2] = *(const half8*)(x1l + o);
            }

    floatx16 acc[2][2];
    #pragma unroll
    for (int a = 0; a < 2; a++)
        #pragma unroll
        for (int b = 0; b < 2; b++)
            #pragma unroll
            for (int i = 0; i < 16; i++) acc[a][b][i] = 0.f;

    __syncthreads();   // DMA drained (vmcnt 0), s_thr/s_invn/cnt_s visible

    // ---- sync-free MFMA sweep: 4 K-chunks x 2 K16-steps x (2x2 tiles x 3 planes) ----
    const int wcb = wc >> 5;
    const int lane8 = lane * 8;
    #pragma unroll
    for (int c = 0; c < 4; c++) {
        #pragma unroll
        for (int k2 = 0; k2 < 2; k2++) {
            half8 bh[2], bl[2];
            #pragma unroll
            for (int v = 0; v < 2; v++) {
                const int ob = (wcb + v) * 4096 + (c * 2 + k2) * 512 + lane8;
                bh[v] = *(const half8*)&Bh[ob];
                bl[v] = *(const half8*)&Bl[ob];
            }
            #pragma unroll
            for (int mt = 0; mt < 2; mt++)
                #pragma unroll
                for (int nt = 0; nt < 2; nt++) {
                    acc[mt][nt] = __builtin_amdgcn_mfma_f32_32x32x16_f16(afl[mt][c][k2], bh[nt], acc[mt][nt], 0, 0, 0);
                    acc[mt][nt] = __builtin_amdgcn_mfma_f32_32x32x16_f16(afh[mt][c][k2], bl[nt], acc[mt][nt], 0, 0, 0);
                    acc[mt][nt] = __builtin_amdgcn_mfma_f32_32x32x16_f16(afh[mt][c][k2], bh[nt], acc[mt][nt], 0, 0, 0);
                }
        }
    }

    // ---- epilogue: normalize, compare vs diag threshold, ballot-count ----
    // C/D layout (32x32): col = lane&31, row = (reg&3) + 8*(reg>>2) + 4*(lane>>5)
    const int cm = lane & 31;
    const int hw = lane >> 5;
    const float iv0 = s_invn[wc + cm];
    const float iv1 = s_invn[wc + 32 + cm];
    const int gc0 = col0 + wc + cm;
    const int gc1 = gc0 + 32;

    #pragma unroll
    for (int mt = 0; mt < 2; mt++) {
        #pragma unroll
        for (int reg = 0; reg < 16; reg++) {
            const int rbase = wr + mt * 32 + (reg & 3) + 8 * (reg >> 2);
            const int rloc  = rbase + 4 * hw;
            const int grow  = row0 + rloc;
            const float t   = s_thr[rloc];
            const bool p0 = (acc[mt][0][reg] * iv0 > t) && (gc0 != grow);
            const bool p1 = (acc[mt][1][reg] * iv1 > t) && (gc1 != grow);
            const unsigned long long b0 = __ballot(p0);
            const unsigned long long b1 = __ballot(p1);
            if (lane == 0) {
                const int clo = __popcll(b0 & 0xffffffffULL) + __popcll(b1 & 0xffffffffULL);
                if (clo) atomicAdd(&cnt_s[rbase], clo);
            } else if (lane == 32) {
                const int chi = __popcll(b0 >> 32) + __popcll(b1 >> 32);
                if (chi) atomicAdd(&cnt_s[rbase + 4], chi);
            }
        }
    }
    __syncthreads();
    if (tid < 128) {
        const int v = cnt_s[tid];
        if (v) atomicAdd(&row_count[row0 + tid], v);
    }
}

// ---------- Kernel B (fallback, proven): in-kernel conversion path ----------
__global__ __launch_bounds__(256) void count_kernel_conv(
    const float* __restrict__ x1, const float* __restrict__ x2,
    const float* __restrict__ invn, const float* __restrict__ thr,
    int* __restrict__ row_count)
{
    __shared__ __align__(16) _Float16 As_hi[4096], As_lo[4096];
    __shared__ __align__(16) _Float16 Bs_hi[4096], Bs_lo[4096];
    __shared__ float s_thr[128], s_invn[128];
    __shared__ int cnt_s[128];

    const int tid  = threadIdx.x;
    const int wave = tid >> 6;
    const int lane = tid & 63;
    const int row0 = blockIdx.y * 128;
    const int col0 = blockIdx.x * 128;
    const int wr = (wave >> 1) * 64;
    const int wc = (wave & 1) * 64;

    if (tid < 128) {
        cnt_s[tid]  = 0;
        s_thr[tid]  = thr[row0 + tid];
        s_invn[tid] = invn[col0 + tid];
    }

    floatx16 acc[2][2];
    #pragma unroll
    for (int a = 0; a < 2; a++)
        #pragma unroll
        for (int b = 0; b < 2; b++)
            #pragma unroll
            for (int i = 0; i < 16; i++) acc[a][b][i] = 0.f;

    const int sr   = tid >> 1;
    const int sks2 = tid & 1;
    const int wbase = ((sr >> 5) * 2 + sks2) * 512 + (sr & 31) * 8;
    const size_t ga = (size_t)(row0 + sr) * KDIM + sks2 * 16;
    const size_t gb = (size_t)(col0 + sr) * KDIM + sks2 * 16;

    const int wrg = wr >> 5;
    const int wcg = wc >> 5;
    const int lane8 = lane * 8;

    for (int kc = 0; kc < KDIM; kc += 32) {
        __syncthreads();
        {
            const float* p = &x1[ga + kc];
            float v[16];
            *(float4*)&v[0]  = *(const float4*)(p);
            *(float4*)&v[4]  = *(const float4*)(p + 4);
            *(float4*)&v[8]  = *(const float4*)(p + 8);
            *(float4*)&v[12] = *(const float4*)(p + 12);
            half8 h0, h1, l0, l1;
            #pragma unroll
            for (int i = 0; i < 8; i++) {
                _Float16 h = (_Float16)v[i];
                h0[i] = h; l0[i] = (_Float16)(v[i] - (float)h);
                _Float16 g = (_Float16)v[i + 8];
                h1[i] = g; l1[i] = (_Float16)(v[i + 8] - (float)g);
            }
            *(half8*)&As_hi[wbase]       = h0;
            *(half8*)&As_hi[wbase + 256] = h1;
            *(half8*)&As_lo[wbase]       = l0;
            *(half8*)&As_lo[wbase + 256] = l1;
        }
        {
            const float* p = &x2[gb + kc];
            float v[16];
            *(float4*)&v[0]  = *(const float4*)(p);
            *(float4*)&v[4]  = *(const float4*)(p + 4);
            *(float4*)&v[8]  = *(const float4*)(p + 8);
            *(float4*)&v[12] = *(const float4*)(p + 12);
            half8 h0, h1, l0, l1;
            #pragma unroll
            for (int i = 0; i < 8; i++) {
                _Float16 h = (_Float16)v[i];
                h0[i] = h; l0[i] = (_Float16)(v[i] - (float)h);
                _Float16 g = (_Float16)v[i + 8];
                h1[i] = g; l1[i] = (_Float16)(v[i + 8] - (float)g);
            }
            *(half8*)&Bs_hi[wbase]       = h0;
            *(half8*)&Bs_hi[wbase + 256] = h1;
            *(half8*)&Bs_lo[wbase]       = l0;
            *(half8*)&Bs_lo[wbase + 256] = l1;
        }
        __syncthreads();

        #pragma unroll
        for (int ks2 = 0; ks2 < 2; ks2++) {
            half8 ah[2], al[2], bh[2], bl[2];
            #pragma unroll
            for (int t = 0; t < 2; t++) {
                const int oa = ((wrg + t) * 2 + ks2) * 512 + lane8;
                ah[t] = *(const half8*)&As_hi[oa];
                al[t] = *(const half8*)&As_lo[oa];
                const int ob = ((wcg + t) * 2 + ks2) * 512 + lane8;
                bh[t] = *(const half8*)&Bs_hi[ob];
                bl[t] = *(const half8*)&Bs_lo[ob];
            }
            #pragma unroll
            for (int mt = 0; mt < 2; mt++)
                #pragma unroll
                for (int nt = 0; nt < 2; nt++) {
                    acc[mt][nt] = __builtin_amdgcn_mfma_f32_32x32x16_f16(al[mt], bh[nt], acc[mt][nt], 0, 0, 0);
                    acc[mt][nt] = __builtin_amdgcn_mfma_f32_32x32x16_f16(ah[mt], bl[nt], acc[mt][nt], 0, 0, 0);
                    acc[mt][nt] = __builtin_amdgcn_mfma_f32_32x32x16_f16(ah[mt], bh[nt], acc[mt][nt], 0, 0, 0);
                }
        }
    }

    const int cm = lane & 31;
    const int hw = lane >> 5;
    const float iv0 = s_invn[wc + cm];
    const float iv1 = s_invn[wc + 32 + cm];
    const int gc0 = col0 + wc + cm;
    const int gc1 = gc0 + 32;

    #pragma unroll
    for (int mt = 0; mt < 2; mt++) {
        #pragma unroll
        for (int reg = 0; reg < 16; reg++) {
            const int rbase = wr + mt * 32 + (reg & 3) + 8 * (reg >> 2);
            const int rloc  = rbase + 4 * hw;
            const int grow  = row0 + rloc;
            const float t   = s_thr[rloc];
            const bool p0 = (acc[mt][0][reg] * iv0 > t) && (gc0 != grow);
            const bool p1 = (acc[mt][1][reg] * iv1 > t) && (gc1 != grow);
            const unsigned long long b0 = __ballot(p0);
            const unsigned long long b1 = __ballot(p1);
            if (lane == 0) {
                const int clo = __popcll(b0 & 0xffffffffULL) + __popcll(b1 & 0xffffffffULL);
                if (clo) atomicAdd(&cnt_s[rbase], clo);
            } else if (lane == 32) {
                const int chi = __popcll(b0 >> 32) + __popcll(b1 >> 32);
                if (chi) atomicAdd(&cnt_s[rbase + 4], chi);
            }
        }
    }
    __syncthreads();
    if (tid < 128) {
        const int v = cnt_s[tid];
        if (v) atomicAdd(&row_count[row0 + tid], v);
    }
}

// ---------- Kernel C: final reduction ----------
__global__ __launch_bounds__(1024) void finalize_kernel(
    const int* __restrict__ row_count, float* __restrict__ out, int B, int nper)
{
    __shared__ int wsum[16];
    const int t = threadIdx.x;
    int c = 0;
    for (int i = t; i < B; i += 1024) c += (row_count[i] < nper) ? 1 : 0;
    #pragma unroll
    for (int m = 32; m > 0; m >>= 1) c += __shfl_xor(c, m);
    if ((t & 63) == 0) wsum[t >> 6] = c;
    __syncthreads();
    if (t == 0) {
        int tot = 0;
        #pragma unroll
        for (int w = 0; w < 16; w++) tot += wsum[w];
        out[0] = (float)tot / (float)B;
    }
}

extern "C" void kernel_launch(void* const* d_in, const int* in_sizes, int n_in,
                              void* d_out, int out_size, void* d_ws, size_t ws_size,
                              hipStream_t stream)
{
    const float* x1 = (const float*)d_in[0];
    const float* x2 = (const float*)d_in[1];
    const int B = in_sizes[0] / KDIM;     // 8192
    const int S = in_sizes[1] / KDIM;     // 8192
    const int nper = S / 100 + 1;         // 82

    float* invn      = (float*)d_ws;
    float* thr       = invn + S;
    int*   row_count = (int*)(thr + B);

    uintptr_t ap = ((uintptr_t)(row_count + B) + 15) & ~(uintptr_t)15;
    _Float16* x1h = (_Float16*)ap;
    _Float16* x1l = x1h + (size_t)B * KDIM;
    _Float16* x2h = x1l + (size_t)B * KDIM;
    _Float16* x2l = x2h + (size_t)S * KDIM;
    const size_t need = (size_t)((char*)(x2l + (size_t)S * KDIM) - (char*)d_ws);
    // fast path needs ws for planes and 128|B, 128|S (fragment-major superblocks)
    const int fast = (ws_size >= need && (B % 128) == 0 && (S % 128) == 0) ? 1 : 0;

    const int mx = (B > S) ? B : S;
    prep_kernel<<<(mx + 3) / 4, 256, 0, stream>>>(
        x1, x2, invn, thr, row_count,
        (unsigned*)x1h, (unsigned*)x1l, (unsigned*)x2h, (unsigned*)x2l,
        B, S, fast);

    dim3 grid(S / 128, B / 128);
    if (fast)
        count_kernel_fast<<<grid, 256, 0, stream>>>(x1h, x1l, x2h, x2l, invn, thr, row_count);
    else
        count_kernel_conv<<<grid, 256, 0, stream>>>(x1, x2, invn, thr, row_count);

    finalize_kernel<<<1, 1024, 0, stream>>>(row_count, (float*)d_out, B, nper);
}

// Round 4
// 125.160 us; speedup vs baseline: 1.1610x; 1.1610x over previous
//
#include <hip/hip_runtime.h>

// out = mean_i( rank_of_diag(cos_sim(x1,x2))_i < nper ), nper = S/100+1.
// rank_i = #{ j != i : dot(x1_i,x2_j)*inv||x2_j|| > dot(x1_i,x2_i)*inv||x2_i|| }
// GEMM via fp16x3 (Markidis split) MFMA: x=hi+lo; hi*hi + hi*lo + lo*hi.
// Dropped lo*lo ~2^-22 rel/term -> dot err ~3e-6 << 4.5e-3 order-stat spacing.
//
// R4: ZERO-LDS, ZERO-BARRIER main loop. Planes are fragment-major in global
// (prep pre-swizzles), so every A/B fragment is a contiguous 1KB block per
// wave = one perfectly-coalesced dwordx4 per lane, streamed from L2.
// Each wave owns a 64x64 tile; 8 unrolled steps x {8 loads + 12 MFMAs}; no
// __syncthreads until the epilogue. R3 evidence: compiler already streams
// frags (VGPR=104, loads sunk into loop) and 64KB LDS merely capped occupancy
// at 2 blocks/CU; this removes the LDS/barrier cost entirely and lets
// ~12 waves/CU self-schedule (MFMA floor 20.5us, L2 leg ~31us, overlapped).
//
// Fragment-major plane layout (per plane, halves):
//   addr(row,k) = (row>>5)*4096 + ((k>>5)*2 + ((k>>4)&1))*512
//               + ((k>>3)&1)*256 + (row&31)*8 + (k&7)
// -> a 32-row x 16-half fragment is one contiguous 1KB block, lane reads 16B
//    at block_base + lane*8 halves.

#define KDIM 128

typedef _Float16 half8 __attribute__((ext_vector_type(8)));
typedef float floatx16 __attribute__((ext_vector_type(16)));

// ---------- Kernel A: 1/||x2||, diag threshold, zero counters, fragment-major fp16 planes ----------
__global__ __launch_bounds__(256) void prep_kernel(
    const float* __restrict__ x1, const float* __restrict__ x2,
    float* __restrict__ invn, float* __restrict__ thr,
    int* __restrict__ row_count,
    unsigned* __restrict__ x1h, unsigned* __restrict__ x1l,
    unsigned* __restrict__ x2h, unsigned* __restrict__ x2l,
    int B, int S, int wplanes)
{
    const int wave = threadIdx.x >> 6;
    const int lane = threadIdx.x & 63;
    const int row = blockIdx.x * 4 + wave;
    if (row >= S && row >= B) return;

    float s22 = 0.f, s12 = 0.f;
    float2 a = make_float2(0.f, 0.f), b = make_float2(0.f, 0.f);
    if (row < B) a = ((const float2*)&x1[(size_t)row * KDIM])[lane];
    if (row < S) {
        b = ((const float2*)&x2[(size_t)row * KDIM])[lane];
        s22 = fmaf(b.x, b.x, b.y * b.y);
        s12 = fmaf(a.x, b.x, a.y * b.y);
    }

    if (wplanes) {
        // k = 2*lane, pair (k,k+1) shares one u32 slot.
        // u32 index: br*2048 + (c*2+ks2)*256 + hw*128 + fr*4 + q
        const int iu = (row >> 5) * 2048
                     + ((lane >> 4) * 2 + ((lane >> 3) & 1)) * 256
                     + ((lane >> 2) & 1) * 128
                     + (row & 31) * 4 + (lane & 3);
        if (row < B) {
            union { _Float16 h[2]; unsigned u; } hh, ll;
            hh.h[0] = (_Float16)a.x; ll.h[0] = (_Float16)(a.x - (float)hh.h[0]);
            hh.h[1] = (_Float16)a.y; ll.h[1] = (_Float16)(a.y - (float)hh.h[1]);
            x1h[iu] = hh.u;
            x1l[iu] = ll.u;
        }
        if (row < S) {
            union { _Float16 h[2]; unsigned u; } hh, ll;
            hh.h[0] = (_Float16)b.x; ll.h[0] = (_Float16)(b.x - (float)hh.h[0]);
            hh.h[1] = (_Float16)b.y; ll.h[1] = (_Float16)(b.y - (float)hh.h[1]);
            x2h[iu] = hh.u;
            x2l[iu] = ll.u;
        }
    }

    #pragma unroll
    for (int m = 32; m > 0; m >>= 1) {
        s22 += __shfl_xor(s22, m);
        s12 += __shfl_xor(s12, m);
    }
    if (lane == 0) {
        if (row < S) {
            float iv = rsqrtf(s22);
            invn[row] = iv;
            if (row < B) thr[row] = s12 * iv;
        }
        if (row < B) row_count[row] = 0;
    }
}

// ---------- Kernel B (fast): zero-LDS zero-barrier L2-streamed fp16x3 GEMM + count ----------
// Block = 128x128 (4 waves, 2x2 of 64x64 wave tiles). No staging; every
// fragment streamed from the fragment-major planes (L2-resident).
__global__ __launch_bounds__(256, 3) void count_kernel_fast(
    const _Float16* __restrict__ x1h, const _Float16* __restrict__ x1l,
    const _Float16* __restrict__ x2h, const _Float16* __restrict__ x2l,
    const float* __restrict__ invn, const float* __restrict__ thr,
    int* __restrict__ row_count)
{
    __shared__ float s_thr[128], s_invn[128];
    __shared__ int cnt_s[128];

    const int tid  = threadIdx.x;
    const int wave = tid >> 6;
    const int lane = tid & 63;
    const int row0 = blockIdx.y * 128;
    const int col0 = blockIdx.x * 128;
    const int wr = (wave >> 1) * 64;   // wave row offset
    const int wc = (wave & 1) * 64;    // wave col offset

    if (tid < 128) {
        cnt_s[tid]  = 0;
        s_thr[tid]  = thr[row0 + tid];
        s_invn[tid] = invn[col0 + tid];
    }

    // per-wave fragment stream bases (lane-contiguous 16B within 1KB blocks)
    const size_t la8 = (size_t)lane * 8;
    const _Float16* pah = x1h + (size_t)((row0 + wr) >> 5) * 4096 + la8;
    const _Float16* pal = x1l + (size_t)((row0 + wr) >> 5) * 4096 + la8;
    const _Float16* pbh = x2h + (size_t)((col0 + wc) >> 5) * 4096 + la8;
    const _Float16* pbl = x2l + (size_t)((col0 + wc) >> 5) * 4096 + la8;

    floatx16 acc[2][2];
    #pragma unroll
    for (int a = 0; a < 2; a++)
        #pragma unroll
        for (int b = 0; b < 2; b++)
            #pragma unroll
            for (int i = 0; i < 16; i++) acc[a][b][i] = 0.f;

    // ---- barrier-free MFMA sweep: 8 K16-steps x {8 coalesced loads + 12 MFMAs} ----
    #pragma unroll
    for (int c = 0; c < 4; c++) {
        #pragma unroll
        for (int k2 = 0; k2 < 2; k2++) {
            const int so = (c * 2 + k2) * 512;
            half8 ah[2], al[2], bh[2], bl[2];
            #pragma unroll
            for (int u = 0; u < 2; u++) {
                ah[u] = *(const half8*)(pah + (size_t)u * 4096 + so);
                al[u] = *(const half8*)(pal + (size_t)u * 4096 + so);
                bh[u] = *(const half8*)(pbh + (size_t)u * 4096 + so);
                bl[u] = *(const half8*)(pbl + (size_t)u * 4096 + so);
            }
            #pragma unroll
            for (int mt = 0; mt < 2; mt++)
                #pragma unroll
                for (int nt = 0; nt < 2; nt++) {
                    acc[mt][nt] = __builtin_amdgcn_mfma_f32_32x32x16_f16(al[mt], bh[nt], acc[mt][nt], 0, 0, 0);
                    acc[mt][nt] = __builtin_amdgcn_mfma_f32_32x32x16_f16(ah[mt], bl[nt], acc[mt][nt], 0, 0, 0);
                    acc[mt][nt] = __builtin_amdgcn_mfma_f32_32x32x16_f16(ah[mt], bh[nt], acc[mt][nt], 0, 0, 0);
                }
        }
    }

    __syncthreads();   // s_thr/s_invn/cnt_s init visible to all waves

    // ---- epilogue: normalize, compare vs diag threshold, ballot-count ----
    // C/D layout (32x32): col = lane&31, row = (reg&3) + 8*(reg>>2) + 4*(lane>>5)
    const int cm = lane & 31;
    const int hw = lane >> 5;
    const float iv0 = s_invn[wc + cm];
    const float iv1 = s_invn[wc + 32 + cm];
    const int gc0 = col0 + wc + cm;
    const int gc1 = gc0 + 32;

    #pragma unroll
    for (int mt = 0; mt < 2; mt++) {
        #pragma unroll
        for (int reg = 0; reg < 16; reg++) {
            const int rbase = wr + mt * 32 + (reg & 3) + 8 * (reg >> 2);
            const int rloc  = rbase + 4 * hw;
            const int grow  = row0 + rloc;
            const float t   = s_thr[rloc];
            const bool p0 = (acc[mt][0][reg] * iv0 > t) && (gc0 != grow);
            const bool p1 = (acc[mt][1][reg] * iv1 > t) && (gc1 != grow);
            const unsigned long long b0 = __ballot(p0);
            const unsigned long long b1 = __ballot(p1);
            if (lane == 0) {
                const int clo = __popcll(b0 & 0xffffffffULL) + __popcll(b1 & 0xffffffffULL);
                if (clo) atomicAdd(&cnt_s[rbase], clo);
            } else if (lane == 32) {
                const int chi = __popcll(b0 >> 32) + __popcll(b1 >> 32);
                if (chi) atomicAdd(&cnt_s[rbase + 4], chi);
            }
        }
    }
    __syncthreads();
    if (tid < 128) {
        const int v = cnt_s[tid];
        if (v) atomicAdd(&row_count[row0 + tid], v);
    }
}

// ---------- Kernel B (fallback, proven): in-kernel conversion path ----------
__global__ __launch_bounds__(256) void count_kernel_conv(
    const float* __restrict__ x1, const float* __restrict__ x2,
    const float* __restrict__ invn, const float* __restrict__ thr,
    int* __restrict__ row_count)
{
    __shared__ __align__(16) _Float16 As_hi[4096], As_lo[4096];
    __shared__ __align__(16) _Float16 Bs_hi[4096], Bs_lo[4096];
    __shared__ float s_thr[128], s_invn[128];
    __shared__ int cnt_s[128];

    const int tid  = threadIdx.x;
    const int wave = tid >> 6;
    const int lane = tid & 63;
    const int row0 = blockIdx.y * 128;
    const int col0 = blockIdx.x * 128;
    const int wr = (wave >> 1) * 64;
    const int wc = (wave & 1) * 64;

    if (tid < 128) {
        cnt_s[tid]  = 0;
        s_thr[tid]  = thr[row0 + tid];
        s_invn[tid] = invn[col0 + tid];
    }

    floatx16 acc[2][2];
    #pragma unroll
    for (int a = 0; a < 2; a++)
        #pragma unroll
        for (int b = 0; b < 2; b++)
            #pragma unroll
            for (int i = 0; i < 16; i++) acc[a][b][i] = 0.f;

    const int sr   = tid >> 1;
    const int sks2 = tid & 1;
    const int wbase = ((sr >> 5) * 2 + sks2) * 512 + (sr & 31) * 8;
    const size_t ga = (size_t)(row0 + sr) * KDIM + sks2 * 16;
    const size_t gb = (size_t)(col0 + sr) * KDIM + sks2 * 16;

    const int wrg = wr >> 5;
    const int wcg = wc >> 5;
    const int lane8 = lane * 8;

    for (int kc = 0; kc < KDIM; kc += 32) {
        __syncthreads();
        {
            const float* p = &x1[ga + kc];
            float v[16];
            *(float4*)&v[0]  = *(const float4*)(p);
            *(float4*)&v[4]  = *(const float4*)(p + 4);
            *(float4*)&v[8]  = *(const float4*)(p + 8);
            *(float4*)&v[12] = *(const float4*)(p + 12);
            half8 h0, h1, l0, l1;
            #pragma unroll
            for (int i = 0; i < 8; i++) {
                _Float16 h = (_Float16)v[i];
                h0[i] = h; l0[i] = (_Float16)(v[i] - (float)h);
                _Float16 g = (_Float16)v[i + 8];
                h1[i] = g; l1[i] = (_Float16)(v[i + 8] - (float)g);
            }
            *(half8*)&As_hi[wbase]       = h0;
            *(half8*)&As_hi[wbase + 256] = h1;
            *(half8*)&As_lo[wbase]       = l0;
            *(half8*)&As_lo[wbase + 256] = l1;
        }
        {
            const float* p = &x2[gb + kc];
            float v[16];
            *(float4*)&v[0]  = *(const float4*)(p);
            *(float4*)&v[4]  = *(const float4*)(p + 4);
            *(float4*)&v[8]  = *(const float4*)(p + 8);
            *(float4*)&v[12] = *(const float4*)(p + 12);
            half8 h0, h1, l0, l1;
            #pragma unroll
            for (int i = 0; i < 8; i++) {
                _Float16 h = (_Float16)v[i];
                h0[i] = h; l0[i] = (_Float16)(v[i] - (float)h);
                _Float16 g = (_Float16)v[i + 8];
                h1[i] = g; l1[i] = (_Float16)(v[i + 8] - (float)g);
            }
            *(half8*)&Bs_hi[wbase]       = h0;
            *(half8*)&Bs_hi[wbase + 256] = h1;
            *(half8*)&Bs_lo[wbase]       = l0;
            *(half8*)&Bs_lo[wbase + 256] = l1;
        }
        __syncthreads();

        #pragma unroll
        for (int ks2 = 0; ks2 < 2; ks2++) {
            half8 ah[2], al[2], bh[2], bl[2];
            #pragma unroll
            for (int t = 0; t < 2; t++) {
                const int oa = ((wrg + t) * 2 + ks2) * 512 + lane8;
                ah[t] = *(const half8*)&As_hi[oa];
                al[t] = *(const half8*)&As_lo[oa];
                const int ob = ((wcg + t) * 2 + ks2) * 512 + lane8;
                bh[t] = *(const half8*)&Bs_hi[ob];
                bl[t] = *(const half8*)&Bs_lo[ob];
            }
            #pragma unroll
            for (int mt = 0; mt < 2; mt++)
                #pragma unroll
                for (int nt = 0; nt < 2; nt++) {
                    acc[mt][nt] = __builtin_amdgcn_mfma_f32_32x32x16_f16(al[mt], bh[nt], acc[mt][nt], 0, 0, 0);
                    acc[mt][nt] = __builtin_amdgcn_mfma_f32_32x32x16_f16(ah[mt], bl[nt], acc[mt][nt], 0, 0, 0);
                    acc[mt][nt] = __builtin_amdgcn_mfma_f32_32x32x16_f16(ah[mt], bh[nt], acc[mt][nt], 0, 0, 0);
                }
        }
    }

    const int cm = lane & 31;
    const int hw = lane >> 5;
    const float iv0 = s_invn[wc + cm];
    const float iv1 = s_invn[wc + 32 + cm];
    const int gc0 = col0 + wc + cm;
    const int gc1 = gc0 + 32;

    #pragma unroll
    for (int mt = 0; mt < 2; mt++) {
        #pragma unroll
        for (int reg = 0; reg < 16; reg++) {
            const int rbase = wr + mt * 32 + (reg & 3) + 8 * (reg >> 2);
            const int rloc  = rbase + 4 * hw;
            const int grow  = row0 + rloc;
            const float t   = s_thr[rloc];
            const bool p0 = (acc[mt][0][reg] * iv0 > t) && (gc0 != grow);
            const bool p1 = (acc[mt][1][reg] * iv1 > t) && (gc1 != grow);
            const unsigned long long b0 = __ballot(p0);
            const unsigned long long b1 = __ballot(p1);
            if (lane == 0) {
                const int clo = __popcll(b0 & 0xffffffffULL) + __popcll(b1 & 0xffffffffULL);
                if (clo) atomicAdd(&cnt_s[rbase], clo);
            } else if (lane == 32) {
                const int chi = __popcll(b0 >> 32) + __popcll(b1 >> 32);
                if (chi) atomicAdd(&cnt_s[rbase + 4], chi);
            }
        }
    }
    __syncthreads();
    if (tid < 128) {
        const int v = cnt_s[tid];
        if (v) atomicAdd(&row_count[row0 + tid], v);
    }
}

// ---------- Kernel C: final reduction ----------
__global__ __launch_bounds__(1024) void finalize_kernel(
    const int* __restrict__ row_count, float* __restrict__ out, int B, int nper)
{
    __shared__ int wsum[16];
    const int t = threadIdx.x;
    int c = 0;
    for (int i = t; i < B; i += 1024) c += (row_count[i] < nper) ? 1 : 0;
    #pragma unroll
    for (int m = 32; m > 0; m >>= 1) c += __shfl_xor(c, m);
    if ((t & 63) == 0) wsum[t >> 6] = c;
    __syncthreads();
    if (t == 0) {
        int tot = 0;
        #pragma unroll
        for (int w = 0; w < 16; w++) tot += wsum[w];
        out[0] = (float)tot / (float)B;
    }
}

extern "C" void kernel_launch(void* const* d_in, const int* in_sizes, int n_in,
                              void* d_out, int out_size, void* d_ws, size_t ws_size,
                              hipStream_t stream)
{
    const float* x1 = (const float*)d_in[0];
    const float* x2 = (const float*)d_in[1];
    const int B = in_sizes[0] / KDIM;     // 8192
    const int S = in_sizes[1] / KDIM;     // 8192
    const int nper = S / 100 + 1;         // 82

    float* invn      = (float*)d_ws;
    float* thr       = invn + S;
    int*   row_count = (int*)(thr + B);

    uintptr_t ap = ((uintptr_t)(row_count + B) + 15) & ~(uintptr_t)15;
    _Float16* x1h = (_Float16*)ap;
    _Float16* x1l = x1h + (size_t)B * KDIM;
    _Float16* x2h = x1l + (size_t)B * KDIM;
    _Float16* x2l = x2h + (size_t)S * KDIM;
    const size_t need = (size_t)((char*)(x2l + (size_t)S * KDIM) - (char*)d_ws);
    // fast path needs ws for planes and 128|B, 128|S (fragment-major superblocks)
    const int fast = (ws_size >= need && (B % 128) == 0 && (S % 128) == 0) ? 1 : 0;

    const int mx = (B > S) ? B : S;
    prep_kernel<<<(mx + 3) / 4, 256, 0, stream>>>(
        x1, x2, invn, thr, row_count,
        (unsigned*)x1h, (unsigned*)x1l, (unsigned*)x2h, (unsigned*)x2l,
        B, S, fast);

    dim3 grid(S / 128, B / 128);
    if (fast)
        count_kernel_fast<<<grid, 256, 0, stream>>>(x1h, x1l, x2h, x2l, invn, thr, row_count);
    else
        count_kernel_conv<<<grid, 256, 0, stream>>>(x1, x2, invn, thr, row_count);

    finalize_kernel<<<1, 1024, 0, stream>>>(row_count, (float*)d_out, B, nper);
}